// Round 2
// baseline (179.653 us; speedup 1.0000x reference)
//
#include <hip/hip_runtime.h>
#include <math.h>

#define E_DIM 768
#define S_LEN 1024
#define B_SZ 2
#define H_CNT 12
#define D_HEAD 64
#define M_DIM 768
#define Q_STRIDE 4
#define N_FC1 771            // only M+Q-1 columns of fc1 are consumed

typedef __attribute__((ext_vector_type(8))) short bf16x8;
typedef __attribute__((ext_vector_type(4))) float f32x4;

#define AS1 __attribute__((address_space(1)))
#define AS3 __attribute__((address_space(3)))

__device__ __forceinline__ void gld_lds16(void* lds, const void* g) {
    __builtin_amdgcn_global_load_lds((const AS1 void*)g, (AS3 void*)lds, 16, 0, 0);
}

__device__ __forceinline__ short f2bf(float f) {
    unsigned u = __float_as_uint(f);
    unsigned r = (u + 0x7fffu + ((u >> 16) & 1u)) >> 16;
    return (short)r;
}

__device__ __forceinline__ float bf2f(short s) {
    return __uint_as_float(((unsigned)(unsigned short)s) << 16);
}

// ---------------- block reduction helper (256 threads, 4 waves) ------------

__device__ __forceinline__ float block_reduce_sum(float v, volatile float* red) {
#pragma unroll
    for (int off = 32; off > 0; off >>= 1) v += __shfl_xor(v, off);
    __syncthreads();
    if ((threadIdx.x & 63) == 0) red[threadIdx.x >> 6] = v;
    __syncthreads();
    return red[0] + red[1] + red[2] + red[3];
}

// ------------- preamble: ln1 + bias concat + weight conversion, one grid ---

__global__ __launch_bounds__(256) void preamble(
        const float* __restrict__ Wq, const float* __restrict__ Wk,
        const float* __restrict__ Wv, const float* __restrict__ Wo,
        const float* __restrict__ fc1W, const float* __restrict__ vqcW,
        const float* __restrict__ fc2W, short* __restrict__ dst,
        const float* __restrict__ bq, const float* __restrict__ bk,
        const float* __restrict__ bv, float* __restrict__ bqkv,
        const float* __restrict__ x, const float* __restrict__ ln1_w,
        const float* __restrict__ ln1_b, short* __restrict__ actb) {
    __shared__ float red[4];
    int tid = threadIdx.x;
    if (blockIdx.x < 2048) {          // ln1
        int row = blockIdx.x;
        const float* xr = x + (size_t)row * E_DIM;
        float v0 = xr[tid], v1 = xr[tid + 256], v2 = xr[tid + 512];
        float s = block_reduce_sum(v0 + v1 + v2, red);
        float mu = s * (1.0f / E_DIM);
        float d0 = v0 - mu, d1 = v1 - mu, d2 = v2 - mu;
        float var = block_reduce_sum(d0 * d0 + d1 * d1 + d2 * d2, red) * (1.0f / E_DIM);
        float rs = rsqrtf(var + 1e-5f);
        short* orow = actb + (size_t)row * E_DIM;
        orow[tid]       = f2bf(d0 * rs * ln1_w[tid]       + ln1_b[tid]);
        orow[tid + 256] = f2bf(d1 * rs * ln1_w[tid + 256] + ln1_b[tid + 256]);
        orow[tid + 512] = f2bf(d2 * rs * ln1_w[tid + 512] + ln1_b[tid + 512]);
        return;
    }
    if (blockIdx.x == 2048) {         // bias concat
#pragma unroll
        for (int u = 0; u < 9; u++) {
            int i = tid + u * 256;
            float v = (i < 768) ? bq[i] : (i < 1536) ? bk[i - 768] : bv[i - 1536];
            bqkv[i] = v;
        }
        return;
    }
    int t = (blockIdx.x - 2049) * 256 + tid;      // float4 index
    if (t >= 1475136) return;                     // 5900544 / 4
    int e = t * 4;
    const float* src; int off;
    if      (e < 589824)  { src = Wq;   off = e; }
    else if (e < 1179648) { src = Wk;   off = e - 589824; }
    else if (e < 1769472) { src = Wv;   off = e - 1179648; }
    else if (e < 2359296) { src = Wo;   off = e - 1769472; }
    else if (e < 2951424) { src = fc1W; off = e - 2359296; }
    else if (e < 3541248) { src = vqcW; off = e - 2951424; }
    else                  { src = fc2W; off = e - 3541248; }
    float4 v = *(const float4*)(src + off);
    short4 o = make_short4(f2bf(v.x), f2bf(v.y), f2bf(v.z), f2bf(v.w));
    *(short4*)(dst + e) = o;
}

// ---------------- bf16 MFMA NT GEMM (BK=64, double-buffered, MR-templated) -
// MR x 128 tile, BK=64 (two MRx32 sub-slabs), double-buffered (one barrier
// per iteration). LDS 48 KB at MR=64 -> 3 blocks/CU, matching 768-block
// balanced grids (R10). R5/R6 lesson: runtime-branch epilogues flip the
// allocator into a 68-VGPR accumulator-spill regime; keep OUTMODE a
// template + launch_bounds(256,2). XOR k-slot swizzle -> 2-way alias (free).
// OUTMODE: 2 = bias+GELU+bf16 transpose-scatter (vqc); 3 = QKV split;
//          5 = bf16 partial (no bias) at outp + z*spitch.

template <int OUTMODE, int MR>
__global__ __launch_bounds__(256, 2) void gemm_bf16(
        const short* __restrict__ A, int lda,
        const short* __restrict__ W, int ldw,
        const float* __restrict__ bias,
        void* __restrict__ outp, int ldo, size_t spitch,
        short* __restrict__ Kfp, short* __restrict__ Vfp,
        int N, int klen, int dogelu) {
    constexpr int MI = MR / 32;
    constexpr int AH = MR * 32;
    constexpr int NA = MR / 64;
    constexpr int ASL = 2 * AH;
    __shared__ short At[2 * ASL];
    __shared__ short Bt[2 * 8192];
    const int tid = threadIdx.x;
    const int lane = tid & 63;
    const int wave = tid >> 6;
    const int wr = (wave >> 1) * (MI * 16);
    const int wc = (wave & 1) * 64;
    const int ml = lane & 15;
    const int kq = lane >> 4;
    const int row0 = blockIdx.y * MR;
    const int col0 = blockIdx.x * 128;
    const int kbase = blockIdx.z * klen;

    const short* Ag[NA]; int aoff[NA];
#pragma unroll
    for (int u = 0; u < NA; u++) {
        int c = tid + u * 256;
        int am = c >> 2, ak = ((c & 3) ^ ((am >> 1) & 3)) * 8;
        Ag[u] = A + (size_t)(row0 + am) * lda + ak + kbase;
        aoff[u] = c * 8;
    }
    const int c0 = tid, c1 = tid + 256;
    const int bm0 = c0 >> 2, bk0 = (((c0 & 3) ^ ((bm0 >> 1) & 3))) * 8;
    const int bm1 = c1 >> 2, bk1 = (((c1 & 3) ^ ((bm1 >> 1) & 3))) * 8;
    int wrow0 = col0 + bm0; if (wrow0 > N - 1) wrow0 = N - 1;
    int wrow1 = col0 + bm1; if (wrow1 > N - 1) wrow1 = N - 1;
    const short* Wg0 = W + (size_t)wrow0 * ldw + bk0 + kbase;
    const short* Wg1 = W + (size_t)wrow1 * ldw + bk1 + kbase;

    const int kxor = (kq ^ ((ml >> 1) & 3)) * 8;

    f32x4 acc[MI][4];
#pragma unroll
    for (int i = 0; i < MI; i++)
#pragma unroll
        for (int j = 0; j < 4; j++) acc[i][j] = {0.f, 0.f, 0.f, 0.f};

    auto stage = [&](int buf, int k0) {
        short* Ab = At + buf * ASL;
        short* Bb = Bt + buf * 8192;
#pragma unroll
        for (int u = 0; u < NA; u++) {
            gld_lds16(Ab + aoff[u], Ag[u] + k0);
            gld_lds16(Ab + AH + aoff[u], Ag[u] + k0 + 32);
        }
        gld_lds16(Bb + c0 * 8, Wg0 + k0);
        gld_lds16(Bb + c1 * 8, Wg1 + k0);
        gld_lds16(Bb + 4096 + c0 * 8, Wg0 + k0 + 32);
        gld_lds16(Bb + 4096 + c1 * 8, Wg1 + k0 + 32);
    };

    stage(0, 0);
    int cur = 0;
    for (int k0 = 0; k0 < klen; k0 += 64) {
        __syncthreads();
        if (k0 + 64 < klen) stage(cur ^ 1, k0 + 64);
        const short* Ac = At + cur * ASL;
        const short* Bc = Bt + cur * 8192;
#pragma unroll
        for (int half = 0; half < 2; half++) {
            const short* Ah = Ac + half * AH;
            const short* Bh = Bc + half * 4096;
            bf16x8 af[MI], bfr[4];
#pragma unroll
            for (int i = 0; i < MI; i++)
                af[i] = *(const bf16x8*)&Ah[(wr + i * 16 + ml) * 32 + kxor];
#pragma unroll
            for (int j = 0; j < 4; j++)
                bfr[j] = *(const bf16x8*)&Bh[(wc + j * 16 + ml) * 32 + kxor];
#pragma unroll
            for (int i = 0; i < MI; i++)
#pragma unroll
                for (int j = 0; j < 4; j++)
                    acc[i][j] = __builtin_amdgcn_mfma_f32_16x16x32_bf16(af[i], bfr[j], acc[i][j], 0, 0, 0);
        }
        cur ^= 1;
    }

    // epilogue: C/D layout col = lane&15, row = (lane>>4)*4 + reg
#pragma unroll
    for (int i = 0; i < MI; i++) {
#pragma unroll
        for (int j = 0; j < 4; j++) {
#pragma unroll
            for (int rr = 0; rr < 4; rr++) {
                int r = row0 + wr + i * 16 + kq * 4 + rr;
                int c = col0 + wc + j * 16 + ml;
                if (c < N) {
                    float v = acc[i][j][rr];
                    if (OUTMODE < 4) v += bias[c];
                    if (OUTMODE == 2 && dogelu)
                        v = 0.5f * v * (1.0f + erff(v * 0.70710678118654752f));
                    if (OUTMODE == 2) {
                        ((short*)outp)[(size_t)(r >> 2) * ldo + c * 4 + (r & 3)] = f2bf(v);
                    } else if (OUTMODE == 5) {
                        ((short*)outp)[blockIdx.z * spitch + (size_t)r * ldo + c] = f2bf(v);
                    } else if (OUTMODE == 3) {
                        int s = r & 1023, bb = r >> 10;
                        if (c < 768) {
                            ((short*)outp)[(size_t)r * 768 + c] = f2bf(v);
                        } else if (c < 1536) {
                            int df = c - 768; int hh = df >> 6, d = df & 63;
                            int bh2 = bb * 12 + hh;
                            size_t idx = ((size_t)(bh2 * 64 + (s >> 4)) * 2 + (d >> 5)) * 512
                                       + (size_t)((d >> 3) & 3) * 128 + (size_t)(s & 15) * 8 + (d & 7);
                            Kfp[idx] = f2bf(v);
                        } else {
                            int df = c - 1536; int hh = df >> 6, d = df & 63;
                            int bh2 = bb * 12 + hh;
                            size_t idx = ((size_t)(bh2 * 32 + (s >> 5))) * 2048
                                       + (size_t)(d >> 4) * 512 + (size_t)((s >> 3) & 3) * 128
                                       + (size_t)(d & 15) * 8 + (s & 7);
                            Vfp[idx] = f2bf(v);
                        }
                    }
                }
            }
        }
    }
}

// ---------------- split-K reduce kernels -----------------------------------

// Wo partials (4, bf16) + bo + residual x -> x2 fp32, then LN(ln2) -> y bf16
__global__ __launch_bounds__(256) void reduce_wo_ln(
        const short* __restrict__ part, const float* __restrict__ bo,
        const float* __restrict__ x, const float* __restrict__ w,
        const float* __restrict__ bvec, float* __restrict__ x2,
        short* __restrict__ y) {
    __shared__ float red[4];
    int row = blockIdx.x, tid = threadIdx.x;
    const size_t SP = (size_t)2048 * 768;
    const short* pr = part + (size_t)row * 768;
    const float* xr = x + (size_t)row * 768;
    float* x2r = x2 + (size_t)row * 768;
    float v[3];
#pragma unroll
    for (int u = 0; u < 3; u++) {
        int c = tid + u * 256;
        float s = bo[c] + xr[c];
#pragma unroll
        for (int z = 0; z < 4; z++) s += bf2f(pr[z * SP + c]);
        v[u] = s; x2r[c] = s;
    }
    float s = block_reduce_sum(v[0] + v[1] + v[2], red);
    float mu = s * (1.0f / 768.f);
    float d0 = v[0] - mu, d1 = v[1] - mu, d2 = v[2] - mu;
    float var = block_reduce_sum(d0 * d0 + d1 * d1 + d2 * d2, red) * (1.0f / 768.f);
    float rs = rsqrtf(var + 1e-5f);
    short* orow = y + (size_t)row * 768;
    orow[tid]       = f2bf(d0 * rs * w[tid]       + bvec[tid]);
    orow[tid + 256] = f2bf(d1 * rs * w[tid + 256] + bvec[tid + 256]);
    orow[tid + 512] = f2bf(d2 * rs * w[tid + 512] + bvec[tid + 512]);
}

// fc1 partials (4, bf16 [2048][768], cols 0..767) + bias -> expanded slices.
// Cols 768..770 computed here as block-reduced dots y[r].fc1_W[768+k] so the
// fc1 GEMM runs an exact 768-block grid. Avqc[(r*4+q)][m] = h1[r][m+q].
__global__ __launch_bounds__(256) void reduce_fc1_expand(
        const short* __restrict__ part, const float* __restrict__ b,
        const short* __restrict__ y, const short* __restrict__ w768,
        short* __restrict__ Avqc) {
    __shared__ float row[772];
    __shared__ float red[4];
    int r = blockIdx.x, tid = threadIdx.x;
    const size_t SP = (size_t)2048 * 768;
    const short* pr = part + (size_t)r * 768;
#pragma unroll
    for (int u = 0; u < 3; u++) {
        int c = tid + u * 256;
        float s = b[c];
#pragma unroll
        for (int z = 0; z < 4; z++) s += bf2f(pr[z * SP + c]);
        row[c] = s;
    }
    const short* yr = y + (size_t)r * 768;
    float y0 = bf2f(yr[tid]), y1 = bf2f(yr[tid + 256]), y2 = bf2f(yr[tid + 512]);
#pragma unroll
    for (int k = 0; k < 3; k++) {
        const short* wk = w768 + k * 768;
        float s = y0 * bf2f(wk[tid]) + y1 * bf2f(wk[tid + 256]) + y2 * bf2f(wk[tid + 512]);
        s = block_reduce_sum(s, red);
        if (tid == 0) row[768 + k] = s + b[768 + k];
    }
    __syncthreads();
#pragma unroll
    for (int q = 0; q < 4; q++) {
        short* orow = Avqc + (size_t)(r * 4 + q) * 768;
#pragma unroll
        for (int u = 0; u < 3; u++) {
            int m = tid + u * 256;
            orow[m] = f2bf(row[m + q]);
        }
    }
}

// fc2 partials (4, bf16) + bias + residual x2 -> out fp32
__global__ __launch_bounds__(256) void reduce_fc2(
        const short* __restrict__ part, const float* __restrict__ b,
        const float* __restrict__ x2, float* __restrict__ out) {
    int t = blockIdx.x * 256 + threadIdx.x;
    int row = t / 192;
    int c = (t - row * 192) * 4;
    size_t off = (size_t)row * 768 + c;
    const size_t SP = (size_t)2048 * 768;
    float4 bb = *(const float4*)(b + c);
    float4 xx = *(const float4*)(x2 + off);
    float o0 = bb.x + xx.x, o1 = bb.y + xx.y, o2 = bb.z + xx.z, o3 = bb.w + xx.w;
#pragma unroll
    for (int z = 0; z < 4; z++) {
        short4 v = *(const short4*)(part + z * SP + off);
        o0 += bf2f(v.x); o1 += bf2f(v.y); o2 += bf2f(v.z); o3 += bf2f(v.w);
    }
    float4 o = make_float4(o0, o1, o2, o3);
    *(float4*)(out + off) = o;
}

// ---------------- MFMA fused attention, 4-way KV-split, direct-L2 ---------
// R14: R13's direct-L2 reads were right (FETCH 26->4.7 MB) but the 768-block
// grid capped occupancy at 12 waves/CU -> L2 latency un-hidden (VALUBusy
// FELL to 39%). Fix is TLP: 16 q-rows/block, 4 waves each owning a KV
// QUARTER (4 iters of 64 kv), grid 1536 = 6 blocks/CU exact
// (launch_bounds(256,6), LDS ~25 KB, VGPR 56 <= 85 cap) -> 24 waves/CU.
// qn broadcast via 4 __shfl (no LDS, no barrier); main loop barrier-free;
// combine buffer element-major (lanes contiguous -> conflict-free, vs the
// old lane*32 layout = 32-way conflict). XCD swizzle: 1536 = 8 x 192 -> 3
// (b,h) KV sets (768 KB) per XCD L2.

__global__ __launch_bounds__(256, 6) void attn_mfma(
        const short* __restrict__ Qb,    // [2048][768] bf16
        const short* __restrict__ Kf,    // frag-major
        const short* __restrict__ Vf,    // frag-major
        const float* __restrict__ pond,
        short* __restrict__ vals) {      // [2048][768] bf16
    // Pe/Pr: 4 waves x 1152 shorts each region; union'd with the 24 KB
    // combine buffer (3 partial waves x 64 lanes x 32 floats, element-major)
    __shared__ __align__(16) short Pbuf[12288];
    __shared__ float esx[3][16], rsx[3][16];

    const int tid = threadIdx.x;
    const int lane = tid & 63;
    const int wave = tid >> 6;
    const int wp = wave;           // KV quarter 0..3
    const int ml = lane & 15;
    const int kq = lane >> 4;

    // XCD-affinity swizzle (1536 = 8 XCDs x 192 -> bijective)
    const int fid = blockIdx.x;
    const int w = (fid & 7) * 192 + (fid >> 3);
    const int qt = w & 63;          // 16-row q tile
    const int bh = w >> 6;          // 0..23
    const int b = (bh >= 12) ? 1 : 0;
    const int h = bh - b * 12;

    const int qrow = b * S_LEN + qt * 16 + ml;
    const short* qp = Qb + (size_t)qrow * 768 + h * 64 + kq * 8;
    bf16x8 aq0 = *(const bf16x8*)qp;
    bf16x8 aq1 = *(const bf16x8*)(qp + 32);

    float qn_part = 0.f;
#pragma unroll
    for (int e = 0; e < 8; e++) {
        float v0 = bf2f(aq0[e]), v1 = bf2f(aq1[e]);
        qn_part += v0 * v0 + v1 * v1;
    }
    qn_part += __shfl_xor(qn_part, 16);
    qn_part += __shfl_xor(qn_part, 32);
    // lane (kq*4+r) (ml = row index) holds qn of q-row kq*4+r
    float qn_r[4], is_r[4];
#pragma unroll
    for (int r = 0; r < 4; r++) {
        qn_r[r] = __shfl(qn_part, kq * 4 + r);
        is_r[r] = 1.0f / fminf(fmaxf(qn_r[r], 1e-8f), 1e4f);
    }

    f32x4 Oe[4], Or[4];
#pragma unroll
    for (int dt = 0; dt < 4; dt++) { Oe[dt] = {0.f,0.f,0.f,0.f}; Or[dt] = {0.f,0.f,0.f,0.f}; }
    float es_p[4] = {0.f,0.f,0.f,0.f}, rs_p[4] = {0.f,0.f,0.f,0.f};

    const short* KfB = Kf + (size_t)bh * 65536;
    const short* VfB = Vf + (size_t)bh * 65536;
    short* PeW = Pbuf + wave * 1152;
    short* PrW = Pbuf + 4608 + wave * 1152;

    for (int it = 0; it < 4; it++) {
        const short* Kit = KfB + (size_t)(wp * 4 + it) * 4096;
        const short* Vit = VfB + (size_t)(wp * 4 + it) * 4096;

#pragma unroll
        for (int jtl = 0; jtl < 4; jtl++) {
            bf16x8 bk0 = *(const bf16x8*)&Kit[(jtl * 2 + 0) * 512 + lane * 8];
            bf16x8 bk1 = *(const bf16x8*)&Kit[(jtl * 2 + 1) * 512 + lane * 8];
            // inline k-norm for j = jtl*16 + ml (this wave's tile)
            float knp = 0.f;
#pragma unroll
            for (int e = 0; e < 8; e++) {
                float k0v = bf2f(bk0[e]), k1v = bf2f(bk1[e]);
                knp += k0v * k0v + k1v * k1v;
            }
            knp += __shfl_xor(knp, 16);
            knp += __shfl_xor(knp, 32);
            f32x4 c = {0.f,0.f,0.f,0.f};
            c = __builtin_amdgcn_mfma_f32_16x16x32_bf16(aq0, bk0, c, 0, 0, 0);
            c = __builtin_amdgcn_mfma_f32_16x16x32_bf16(aq1, bk1, c, 0, 0, 0);
#pragma unroll
            for (int r = 0; r < 4; r++) {
                float qk = c[r];
                float e = __expf(qk * 0.125f);
                float tt = (2.f * qk - qn_r[r] - knp) * is_r[r];
                float rb = fminf(__expf(tt), 1.0f);
                es_p[r] += e; rs_p[r] += rb;
                PeW[(kq * 4 + r) * 72 + jtl * 16 + ml] = f2bf(e);
                PrW[(kq * 4 + r) * 72 + jtl * 16 + ml] = f2bf(rb);
            }
        }
        // (no barrier: P round-trip is wave-local)

#pragma unroll
        for (int jcl = 0; jcl < 2; jcl++) {
            bf16x8 pa_e = *(const bf16x8*)&PeW[ml * 72 + jcl * 32 + kq * 8];
            bf16x8 pa_r = *(const bf16x8*)&PrW[ml * 72 + jcl * 32 + kq * 8];
#pragma unroll
            for (int dt = 0; dt < 4; dt++) {
                bf16x8 bv = *(const bf16x8*)&Vit[(jcl * 4 + dt) * 512 + lane * 8];
                Oe[dt] = __builtin_amdgcn_mfma_f32_16x16x32_bf16(pa_e, bv, Oe[dt], 0, 0, 0);
                Or[dt] = __builtin_amdgcn_mfma_f32_16x16x32_bf16(pa_r, bv, Or[dt], 0, 0, 0);
            }
        }
    }

    // per-wave es/rs row sums (sum across ml within each kq group)
#pragma unroll
    for (int off = 1; off <= 8; off <<= 1) {
#pragma unroll
        for (int r = 0; r < 4; r++) {
            es_p[r] += __shfl_xor(es_p[r], off);
            rs_p[r] += __shfl_xor(rs_p[r], off);
        }
    }

    // cross-quarter combine in LDS (Pe/Pr region dead after the loop).
    // Element-major layout: cb[e*192 + (wp-1)*64 + lane] -> each LDS
    // instruction has 64 consecutive lanes -> conflict-free.
    __syncthreads();                     // all waves past their last P read
    float* cb = (float*)Pbuf;
    if (wp) {
        float* cl = cb + (wp - 1) * 64 + lane;
#pragma unroll
        for (int dt = 0; dt < 4; dt++)
#pragma unroll
            for (int r = 0; r < 4; r++) {
                cl[(dt * 4 + r) * 192] = Oe[dt][r];
                cl[(16 + dt * 4 + r) * 192] = Or[dt][r];
            }
        if (ml == 0) {
#pragma unroll
            for (int r = 0; r < 4; r++) {
                esx[wp - 1][kq * 4 + r] = es_p[r];
                rsx[wp - 1][kq * 4 + r] = rs_p[r];
            }
        }
    }
    __syncthreads();
    if (wp == 0) {
        float p = pond[0];
        float sv = 1.0f / (1.0f + __expf(-p));
        float p0 = 1.0f - sv, p1 = sv;
        float blendinv = 1.0f / (p0 + p1 + 1e-7f);
        float we[4], wr[4];
#pragma unroll
        for (int r = 0; r < 4; r++) {
            float es = es_p[r] + esx[0][kq * 4 + r] + esx[1][kq * 4 + r] + esx[2][kq * 4 + r];
            float rs = rs_p[r] + rsx[0][kq * 4 + r] + rsx[1][kq * 4 + r] + rsx[2][kq * 4 + r];
            we[r] = p0 * blendinv / es;
            wr[r] = p1 * blendinv / fmaxf(rs, 1e-8f);
        }
#pragma unroll
        for (int dt = 0; dt < 4; dt++) {
#pragma unroll
            for (int r = 0; r < 4; r++) {
                int e0 = dt * 4 + r;
                float oe = Oe[dt][r] + cb[e0 * 192 + lane] + cb[e0 * 192 + 64 + lane]
                         + cb[e0 * 192 + 128 + lane];
                float orr = Or[dt][r] + cb[(16 + e0) * 192 + lane] + cb[(16 + e0) * 192 + 64 + lane]
                          + cb[(16 + e0) * 192 + 128 + lane];
                float v = oe * we[r] + orr * wr[r];
                int token = b * S_LEN + qt * 16 + kq * 4 + r;
                vals[(size_t)token * 768 + h * 64 + dt * 16 + ml] = f2bf(v);
            }
        }
    }
}

// ---------------- launcher -------------------------------------------------

extern "C" void kernel_launch(void* const* d_in, const int* in_sizes, int n_in,
                              void* d_out, int out_size, void* d_ws, size_t ws_size,
                              hipStream_t stream) {
    const float* x     = (const float*)d_in[0];
    const float* ln1_w = (const float*)d_in[1];
    const float* ln1_b = (const float*)d_in[2];
    const float* Wq    = (const float*)d_in[3];
    const float* bq    = (const float*)d_in[4];
    const float* Wk    = (const float*)d_in[5];
    const float* bk    = (const float*)d_in[6];
    const float* Wv    = (const float*)d_in[7];
    const float* bv    = (const float*)d_in[8];
    const float* Wo    = (const float*)d_in[9];
    const float* bo    = (const float*)d_in[10];
    const float* pond  = (const float*)d_in[11];
    const float* ln2_w = (const float*)d_in[12];
    const float* ln2_b = (const float*)d_in[13];
    const float* fc1_W = (const float*)d_in[14];
    const float* fc1_b = (const float*)d_in[15];
    const float* vqc_W = (const float*)d_in[16];
    const float* vqc_b = (const float*)d_in[17];
    const float* fc2_W = (const float*)d_in[18];
    const float* fc2_b = (const float*)d_in[19];
    float* out = (float*)d_out;

    char* p = (char*)d_ws;
    short* Qb   = (short*)p;  p += (size_t)2048 * 768 * 2;
    short* Kfb  = (short*)p;  p += (size_t)2048 * 768 * 2;
    short* Vfb  = (short*)p;  p += (size_t)2048 * 768 * 2;
    float* x2   = (float*)p;  p += (size_t)2048 * 768 * 4;
    float* bqkv = (float*)p;  p += 2304 * 4;
    short* actb = (short*)p;  p += (size_t)2048 * 768 * 2;
    short* g    = (short*)p;  p += (size_t)2048 * 3072 * 2;
    short* Avqc = (short*)p;  p += (size_t)8192 * 768 * 2;
    short* partb = (short*)p; p += (size_t)4 * 2048 * 768 * 2;   // 12.6 MB split-K partials
    short* wreg = (short*)p;  p += (size_t)5900544 * 2;
    short* Wqkvb = wreg;
    short* Wob   = wreg + 1769472;
    short* fc1b  = wreg + 2359296;
    short* vqcb  = wreg + 2951424;
    short* fc2b  = wreg + 3541248;

    dim3 blk(256);
    const size_t SP = (size_t)2048 * 768;

    // 0. preamble: ln1 + bias concat + weight conversion (one grid)
    preamble<<<7812, blk, 0, stream>>>(Wq, Wk, Wv, Wo, fc1_W, vqc_W, fc2_W, wreg,
                                       bq, bk, bv, bqkv, x, ln1_w, ln1_b, actb);
    // 1. fused QKV projection (direct, dbuf, 576 blocks)
    gemm_bf16<3, 64><<<dim3(18, 32, 1), blk, 0, stream>>>(actb, 768, Wqkvb, 768, bqkv,
                                                          Qb, 768, 0, Kfb, Vfb, 2304, 768, 0);
    // 2. MFMA attention, 4-way KV split, 16 q-rows/block, direct-L2 reads,
    //    1536 blocks = 6/CU exact (24 waves/CU), XCD-affinity swizzled
    attn_mfma<<<1536, blk, 0, stream>>>(Qb, Kfb, Vfb, pond, actb);
    // 3. Wo split-K x4 (768 blocks = 3/CU)
    gemm_bf16<5, 64><<<dim3(6, 32, 4), blk, 0, stream>>>(actb, 768, Wob, 768, nullptr,
                                                         partb, 768, SP,
                                                         nullptr, nullptr, 768, 192, 0);
    // 4. reduce + bo + residual(x) -> x2 fp32, fused ln2 -> actb
    reduce_wo_ln<<<2048, blk, 0, stream>>>(partb, bo, x, ln2_w, ln2_b, x2, actb);
    // 5. fc1 split-K x4, cols 0..767 only (768 blocks = 3/CU exact)
    gemm_bf16<5, 64><<<dim3(6, 32, 4), blk, 0, stream>>>(actb, 768, fc1b, 768, nullptr,
                                                         partb, 768, SP,
                                                         nullptr, nullptr, 768, 192, 0);
    // 6. reduce + bias + cols 768..770 dots + expand -> Avqc [8192][768]
    reduce_fc1_expand<<<2048, blk, 0, stream>>>(partb, fc1_b, actb, fc1b + 768 * 768, Avqc);
    // 7. vqc (direct) + bias + gelu + transpose scatter (768 blocks = 3/CU)
    gemm_bf16<2, 64><<<dim3(6, 128, 1), blk, 0, stream>>>(Avqc, 768, vqcb, 768, vqc_b,
                                                          g, 3072, 0, nullptr, nullptr, 768, 768, 1);
    // 8. fc2 split-K x4 (768 blocks = 3/CU)
    gemm_bf16<5, 64><<<dim3(6, 32, 4), blk, 0, stream>>>(g, 3072, fc2b, 3072, nullptr,
                                                         partb, 768, SP,
                                                         nullptr, nullptr, 768, 768, 0);
    // 9. reduce + bias + residual(x2) -> out fp32
    reduce_fc2<<<1536, blk, 0, stream>>>(partb, fc2_b, x2, out);
}

// Round 3
// 158.973 us; speedup vs baseline: 1.1301x; 1.1301x over previous
//
#include <hip/hip_runtime.h>
#include <math.h>

#define E_DIM 768
#define S_LEN 1024
#define B_SZ 2
#define H_CNT 12
#define D_HEAD 64
#define M_DIM 768
#define Q_STRIDE 4
#define N_FC1 771            // only M+Q-1 columns of fc1 are consumed

typedef __attribute__((ext_vector_type(8))) short bf16x8;
typedef __attribute__((ext_vector_type(4))) float f32x4;

#define AS1 __attribute__((address_space(1)))
#define AS3 __attribute__((address_space(3)))

__device__ __forceinline__ void gld_lds16(void* lds, const void* g) {
    __builtin_amdgcn_global_load_lds((const AS1 void*)g, (AS3 void*)lds, 16, 0, 0);
}

__device__ __forceinline__ short f2bf(float f) {
    unsigned u = __float_as_uint(f);
    unsigned r = (u + 0x7fffu + ((u >> 16) & 1u)) >> 16;
    return (short)r;
}

__device__ __forceinline__ float bf2f(short s) {
    return __uint_as_float(((unsigned)(unsigned short)s) << 16);
}

// ---------------- block reduction helper (256 threads, 4 waves) ------------

__device__ __forceinline__ float block_reduce_sum(float v, volatile float* red) {
#pragma unroll
    for (int off = 32; off > 0; off >>= 1) v += __shfl_xor(v, off);
    __syncthreads();
    if ((threadIdx.x & 63) == 0) red[threadIdx.x >> 6] = v;
    __syncthreads();
    return red[0] + red[1] + red[2] + red[3];
}

// ------------- preamble: ln1 + bias concat + weight conversion, one grid ---

__global__ __launch_bounds__(256) void preamble(
        const float* __restrict__ Wq, const float* __restrict__ Wk,
        const float* __restrict__ Wv, const float* __restrict__ Wo,
        const float* __restrict__ fc1W, const float* __restrict__ vqcW,
        const float* __restrict__ fc2W, short* __restrict__ dst,
        const float* __restrict__ bq, const float* __restrict__ bk,
        const float* __restrict__ bv, float* __restrict__ bqkv,
        const float* __restrict__ x, const float* __restrict__ ln1_w,
        const float* __restrict__ ln1_b, short* __restrict__ actb) {
    __shared__ float red[4];
    int tid = threadIdx.x;
    if (blockIdx.x < 2048) {          // ln1
        int row = blockIdx.x;
        const float* xr = x + (size_t)row * E_DIM;
        float v0 = xr[tid], v1 = xr[tid + 256], v2 = xr[tid + 512];
        float s = block_reduce_sum(v0 + v1 + v2, red);
        float mu = s * (1.0f / E_DIM);
        float d0 = v0 - mu, d1 = v1 - mu, d2 = v2 - mu;
        float var = block_reduce_sum(d0 * d0 + d1 * d1 + d2 * d2, red) * (1.0f / E_DIM);
        float rs = rsqrtf(var + 1e-5f);
        short* orow = actb + (size_t)row * E_DIM;
        orow[tid]       = f2bf(d0 * rs * ln1_w[tid]       + ln1_b[tid]);
        orow[tid + 256] = f2bf(d1 * rs * ln1_w[tid + 256] + ln1_b[tid + 256]);
        orow[tid + 512] = f2bf(d2 * rs * ln1_w[tid + 512] + ln1_b[tid + 512]);
        return;
    }
    if (blockIdx.x == 2048) {         // bias concat
#pragma unroll
        for (int u = 0; u < 9; u++) {
            int i = tid + u * 256;
            float v = (i < 768) ? bq[i] : (i < 1536) ? bk[i - 768] : bv[i - 1536];
            bqkv[i] = v;
        }
        return;
    }
    int t = (blockIdx.x - 2049) * 256 + tid;      // float4 index
    if (t >= 1475136) return;                     // 5900544 / 4
    int e = t * 4;
    const float* src; int off;
    if      (e < 589824)  { src = Wq;   off = e; }
    else if (e < 1179648) { src = Wk;   off = e - 589824; }
    else if (e < 1769472) { src = Wv;   off = e - 1179648; }
    else if (e < 2359296) { src = Wo;   off = e - 1769472; }
    else if (e < 2951424) { src = fc1W; off = e - 2359296; }
    else if (e < 3541248) { src = vqcW; off = e - 2951424; }
    else                  { src = fc2W; off = e - 3541248; }
    float4 v = *(const float4*)(src + off);
    short4 o = make_short4(f2bf(v.x), f2bf(v.y), f2bf(v.z), f2bf(v.w));
    *(short4*)(dst + e) = o;
}

// ---------------- bf16 MFMA NT GEMM (BK=64, double-buffered, MR-templated) -
// MR x 128 tile, BK=64 (two MRx32 sub-slabs), double-buffered (one barrier
// per iteration). LDS 48 KB at MR=64 -> 3 blocks/CU, matching 768-block
// balanced grids (R10). R5/R6 lesson: runtime-branch epilogues flip the
// allocator into a 68-VGPR accumulator-spill regime; keep OUTMODE a
// template + launch_bounds(256,2). XOR k-slot swizzle -> 2-way alias (free).
// OUTMODE: 2 = bias+GELU+bf16 transpose-scatter (vqc); 3 = QKV split;
//          5 = bf16 partial (no bias) at outp + z*spitch.

template <int OUTMODE, int MR>
__global__ __launch_bounds__(256, 2) void gemm_bf16(
        const short* __restrict__ A, int lda,
        const short* __restrict__ W, int ldw,
        const float* __restrict__ bias,
        void* __restrict__ outp, int ldo, size_t spitch,
        short* __restrict__ Kfp, short* __restrict__ Vfp,
        int N, int klen, int dogelu) {
    constexpr int MI = MR / 32;
    constexpr int AH = MR * 32;
    constexpr int NA = MR / 64;
    constexpr int ASL = 2 * AH;
    __shared__ short At[2 * ASL];
    __shared__ short Bt[2 * 8192];
    const int tid = threadIdx.x;
    const int lane = tid & 63;
    const int wave = tid >> 6;
    const int wr = (wave >> 1) * (MI * 16);
    const int wc = (wave & 1) * 64;
    const int ml = lane & 15;
    const int kq = lane >> 4;
    const int row0 = blockIdx.y * MR;
    const int col0 = blockIdx.x * 128;
    const int kbase = blockIdx.z * klen;

    const short* Ag[NA]; int aoff[NA];
#pragma unroll
    for (int u = 0; u < NA; u++) {
        int c = tid + u * 256;
        int am = c >> 2, ak = ((c & 3) ^ ((am >> 1) & 3)) * 8;
        Ag[u] = A + (size_t)(row0 + am) * lda + ak + kbase;
        aoff[u] = c * 8;
    }
    const int c0 = tid, c1 = tid + 256;
    const int bm0 = c0 >> 2, bk0 = (((c0 & 3) ^ ((bm0 >> 1) & 3))) * 8;
    const int bm1 = c1 >> 2, bk1 = (((c1 & 3) ^ ((bm1 >> 1) & 3))) * 8;
    int wrow0 = col0 + bm0; if (wrow0 > N - 1) wrow0 = N - 1;
    int wrow1 = col0 + bm1; if (wrow1 > N - 1) wrow1 = N - 1;
    const short* Wg0 = W + (size_t)wrow0 * ldw + bk0 + kbase;
    const short* Wg1 = W + (size_t)wrow1 * ldw + bk1 + kbase;

    const int kxor = (kq ^ ((ml >> 1) & 3)) * 8;

    f32x4 acc[MI][4];
#pragma unroll
    for (int i = 0; i < MI; i++)
#pragma unroll
        for (int j = 0; j < 4; j++) acc[i][j] = {0.f, 0.f, 0.f, 0.f};

    auto stage = [&](int buf, int k0) {
        short* Ab = At + buf * ASL;
        short* Bb = Bt + buf * 8192;
#pragma unroll
        for (int u = 0; u < NA; u++) {
            gld_lds16(Ab + aoff[u], Ag[u] + k0);
            gld_lds16(Ab + AH + aoff[u], Ag[u] + k0 + 32);
        }
        gld_lds16(Bb + c0 * 8, Wg0 + k0);
        gld_lds16(Bb + c1 * 8, Wg1 + k0);
        gld_lds16(Bb + 4096 + c0 * 8, Wg0 + k0 + 32);
        gld_lds16(Bb + 4096 + c1 * 8, Wg1 + k0 + 32);
    };

    stage(0, 0);
    int cur = 0;
    for (int k0 = 0; k0 < klen; k0 += 64) {
        __syncthreads();
        if (k0 + 64 < klen) stage(cur ^ 1, k0 + 64);
        const short* Ac = At + cur * ASL;
        const short* Bc = Bt + cur * 8192;
#pragma unroll
        for (int half = 0; half < 2; half++) {
            const short* Ah = Ac + half * AH;
            const short* Bh = Bc + half * 4096;
            bf16x8 af[MI], bfr[4];
#pragma unroll
            for (int i = 0; i < MI; i++)
                af[i] = *(const bf16x8*)&Ah[(wr + i * 16 + ml) * 32 + kxor];
#pragma unroll
            for (int j = 0; j < 4; j++)
                bfr[j] = *(const bf16x8*)&Bh[(wc + j * 16 + ml) * 32 + kxor];
#pragma unroll
            for (int i = 0; i < MI; i++)
#pragma unroll
                for (int j = 0; j < 4; j++)
                    acc[i][j] = __builtin_amdgcn_mfma_f32_16x16x32_bf16(af[i], bfr[j], acc[i][j], 0, 0, 0);
        }
        cur ^= 1;
    }

    // epilogue: C/D layout col = lane&15, row = (lane>>4)*4 + reg
#pragma unroll
    for (int i = 0; i < MI; i++) {
#pragma unroll
        for (int j = 0; j < 4; j++) {
#pragma unroll
            for (int rr = 0; rr < 4; rr++) {
                int r = row0 + wr + i * 16 + kq * 4 + rr;
                int c = col0 + wc + j * 16 + ml;
                if (c < N) {
                    float v = acc[i][j][rr];
                    if (OUTMODE < 4) v += bias[c];
                    if (OUTMODE == 2 && dogelu)
                        v = 0.5f * v * (1.0f + erff(v * 0.70710678118654752f));
                    if (OUTMODE == 2) {
                        ((short*)outp)[(size_t)(r >> 2) * ldo + c * 4 + (r & 3)] = f2bf(v);
                    } else if (OUTMODE == 5) {
                        ((short*)outp)[blockIdx.z * spitch + (size_t)r * ldo + c] = f2bf(v);
                    } else if (OUTMODE == 3) {
                        int s = r & 1023, bb = r >> 10;
                        if (c < 768) {
                            ((short*)outp)[(size_t)r * 768 + c] = f2bf(v);
                        } else if (c < 1536) {
                            int df = c - 768; int hh = df >> 6, d = df & 63;
                            int bh2 = bb * 12 + hh;
                            size_t idx = ((size_t)(bh2 * 64 + (s >> 4)) * 2 + (d >> 5)) * 512
                                       + (size_t)((d >> 3) & 3) * 128 + (size_t)(s & 15) * 8 + (d & 7);
                            Kfp[idx] = f2bf(v);
                        } else {
                            int df = c - 1536; int hh = df >> 6, d = df & 63;
                            int bh2 = bb * 12 + hh;
                            size_t idx = ((size_t)(bh2 * 32 + (s >> 5))) * 2048
                                       + (size_t)(d >> 4) * 512 + (size_t)((s >> 3) & 3) * 128
                                       + (size_t)(d & 15) * 8 + (s & 7);
                            Vfp[idx] = f2bf(v);
                        }
                    }
                }
            }
        }
    }
}

// ---------------- split-K reduce kernels -----------------------------------

// Wo partials (4, bf16) + bo + residual x -> x2 fp32, then LN(ln2) -> y bf16
__global__ __launch_bounds__(256) void reduce_wo_ln(
        const short* __restrict__ part, const float* __restrict__ bo,
        const float* __restrict__ x, const float* __restrict__ w,
        const float* __restrict__ bvec, float* __restrict__ x2,
        short* __restrict__ y) {
    __shared__ float red[4];
    int row = blockIdx.x, tid = threadIdx.x;
    const size_t SP = (size_t)2048 * 768;
    const short* pr = part + (size_t)row * 768;
    const float* xr = x + (size_t)row * 768;
    float* x2r = x2 + (size_t)row * 768;
    float v[3];
#pragma unroll
    for (int u = 0; u < 3; u++) {
        int c = tid + u * 256;
        float s = bo[c] + xr[c];
#pragma unroll
        for (int z = 0; z < 4; z++) s += bf2f(pr[z * SP + c]);
        v[u] = s; x2r[c] = s;
    }
    float s = block_reduce_sum(v[0] + v[1] + v[2], red);
    float mu = s * (1.0f / 768.f);
    float d0 = v[0] - mu, d1 = v[1] - mu, d2 = v[2] - mu;
    float var = block_reduce_sum(d0 * d0 + d1 * d1 + d2 * d2, red) * (1.0f / 768.f);
    float rs = rsqrtf(var + 1e-5f);
    short* orow = y + (size_t)row * 768;
    orow[tid]       = f2bf(d0 * rs * w[tid]       + bvec[tid]);
    orow[tid + 256] = f2bf(d1 * rs * w[tid + 256] + bvec[tid + 256]);
    orow[tid + 512] = f2bf(d2 * rs * w[tid + 512] + bvec[tid + 512]);
}

// fc1 partials (4, bf16 [2048][768], cols 0..767) + bias -> expanded slices.
// Cols 768..770 computed here as block-reduced dots y[r].fc1_W[768+k] so the
// fc1 GEMM runs an exact 768-block grid. Avqc[(r*4+q)][m] = h1[r][m+q].
__global__ __launch_bounds__(256) void reduce_fc1_expand(
        const short* __restrict__ part, const float* __restrict__ b,
        const short* __restrict__ y, const short* __restrict__ w768,
        short* __restrict__ Avqc) {
    __shared__ float row[772];
    __shared__ float red[4];
    int r = blockIdx.x, tid = threadIdx.x;
    const size_t SP = (size_t)2048 * 768;
    const short* pr = part + (size_t)r * 768;
#pragma unroll
    for (int u = 0; u < 3; u++) {
        int c = tid + u * 256;
        float s = b[c];
#pragma unroll
        for (int z = 0; z < 4; z++) s += bf2f(pr[z * SP + c]);
        row[c] = s;
    }
    const short* yr = y + (size_t)r * 768;
    float y0 = bf2f(yr[tid]), y1 = bf2f(yr[tid + 256]), y2 = bf2f(yr[tid + 512]);
#pragma unroll
    for (int k = 0; k < 3; k++) {
        const short* wk = w768 + k * 768;
        float s = y0 * bf2f(wk[tid]) + y1 * bf2f(wk[tid + 256]) + y2 * bf2f(wk[tid + 512]);
        s = block_reduce_sum(s, red);
        if (tid == 0) row[768 + k] = s + b[768 + k];
    }
    __syncthreads();
#pragma unroll
    for (int q = 0; q < 4; q++) {
        short* orow = Avqc + (size_t)(r * 4 + q) * 768;
#pragma unroll
        for (int u = 0; u < 3; u++) {
            int m = tid + u * 256;
            orow[m] = f2bf(row[m + q]);
        }
    }
}

// fc2 partials (4, bf16) + bias + residual x2 -> out fp32
__global__ __launch_bounds__(256) void reduce_fc2(
        const short* __restrict__ part, const float* __restrict__ b,
        const float* __restrict__ x2, float* __restrict__ out) {
    int t = blockIdx.x * 256 + threadIdx.x;
    int row = t / 192;
    int c = (t - row * 192) * 4;
    size_t off = (size_t)row * 768 + c;
    const size_t SP = (size_t)2048 * 768;
    float4 bb = *(const float4*)(b + c);
    float4 xx = *(const float4*)(x2 + off);
    float o0 = bb.x + xx.x, o1 = bb.y + xx.y, o2 = bb.z + xx.z, o3 = bb.w + xx.w;
#pragma unroll
    for (int z = 0; z < 4; z++) {
        short4 v = *(const short4*)(part + z * SP + off);
        o0 += bf2f(v.x); o1 += bf2f(v.y); o2 += bf2f(v.z); o3 += bf2f(v.w);
    }
    float4 o = make_float4(o0, o1, o2, o3);
    *(float4*)(out + off) = o;
}

// ---------------- MFMA fused attention, 4-way KV-split, direct-L2 ---------
// R15: R14's structure (16 q-rows/block, per-wave KV quarter, 1536 blocks,
// direct-L2 reads, element-major combine) was right, but launch_bounds
// (256,6) capped VGPR at 85 -> the allocator spilled the MFMA accumulators
// INSIDE the KV loop (FETCH 104 MB / WRITE 161 MB of scratch, VGPR_Count
// 40). Back to (256,4): 128-VGPR cap, no-spill regime (R13 compiled the
// same body in 56 VGPR). Occupancy is then LDS-limited at 25 KB -> 6
// blocks/CU, and the 1536-block grid is 6/CU exact -> 24 waves/CU, double
// R13's 12, with zero scratch.

__global__ __launch_bounds__(256, 4) void attn_mfma(
        const short* __restrict__ Qb,    // [2048][768] bf16
        const short* __restrict__ Kf,    // frag-major
        const short* __restrict__ Vf,    // frag-major
        const float* __restrict__ pond,
        short* __restrict__ vals) {      // [2048][768] bf16
    // Pe/Pr: 4 waves x 1152 shorts each region; union'd with the 24 KB
    // combine buffer (3 partial waves x 64 lanes x 32 floats, element-major)
    __shared__ __align__(16) short Pbuf[12288];
    __shared__ float esx[3][16], rsx[3][16];

    const int tid = threadIdx.x;
    const int lane = tid & 63;
    const int wave = tid >> 6;
    const int wp = wave;           // KV quarter 0..3
    const int ml = lane & 15;
    const int kq = lane >> 4;

    // XCD-affinity swizzle (1536 = 8 XCDs x 192 -> bijective)
    const int fid = blockIdx.x;
    const int w = (fid & 7) * 192 + (fid >> 3);
    const int qt = w & 63;          // 16-row q tile
    const int bh = w >> 6;          // 0..23
    const int b = (bh >= 12) ? 1 : 0;
    const int h = bh - b * 12;

    const int qrow = b * S_LEN + qt * 16 + ml;
    const short* qp = Qb + (size_t)qrow * 768 + h * 64 + kq * 8;
    bf16x8 aq0 = *(const bf16x8*)qp;
    bf16x8 aq1 = *(const bf16x8*)(qp + 32);

    float qn_part = 0.f;
#pragma unroll
    for (int e = 0; e < 8; e++) {
        float v0 = bf2f(aq0[e]), v1 = bf2f(aq1[e]);
        qn_part += v0 * v0 + v1 * v1;
    }
    qn_part += __shfl_xor(qn_part, 16);
    qn_part += __shfl_xor(qn_part, 32);
    // lane (kq*4+r) (ml = row index) holds qn of q-row kq*4+r
    float qn_r[4], is_r[4];
#pragma unroll
    for (int r = 0; r < 4; r++) {
        qn_r[r] = __shfl(qn_part, kq * 4 + r);
        is_r[r] = 1.0f / fminf(fmaxf(qn_r[r], 1e-8f), 1e4f);
    }

    f32x4 Oe[4], Or[4];
#pragma unroll
    for (int dt = 0; dt < 4; dt++) { Oe[dt] = {0.f,0.f,0.f,0.f}; Or[dt] = {0.f,0.f,0.f,0.f}; }
    float es_p[4] = {0.f,0.f,0.f,0.f}, rs_p[4] = {0.f,0.f,0.f,0.f};

    const short* KfB = Kf + (size_t)bh * 65536;
    const short* VfB = Vf + (size_t)bh * 65536;
    short* PeW = Pbuf + wave * 1152;
    short* PrW = Pbuf + 4608 + wave * 1152;

    for (int it = 0; it < 4; it++) {
        const short* Kit = KfB + (size_t)(wp * 4 + it) * 4096;
        const short* Vit = VfB + (size_t)(wp * 4 + it) * 4096;

#pragma unroll
        for (int jtl = 0; jtl < 4; jtl++) {
            bf16x8 bk0 = *(const bf16x8*)&Kit[(jtl * 2 + 0) * 512 + lane * 8];
            bf16x8 bk1 = *(const bf16x8*)&Kit[(jtl * 2 + 1) * 512 + lane * 8];
            // inline k-norm for j = jtl*16 + ml (this wave's tile)
            float knp = 0.f;
#pragma unroll
            for (int e = 0; e < 8; e++) {
                float k0v = bf2f(bk0[e]), k1v = bf2f(bk1[e]);
                knp += k0v * k0v + k1v * k1v;
            }
            knp += __shfl_xor(knp, 16);
            knp += __shfl_xor(knp, 32);
            f32x4 c = {0.f,0.f,0.f,0.f};
            c = __builtin_amdgcn_mfma_f32_16x16x32_bf16(aq0, bk0, c, 0, 0, 0);
            c = __builtin_amdgcn_mfma_f32_16x16x32_bf16(aq1, bk1, c, 0, 0, 0);
#pragma unroll
            for (int r = 0; r < 4; r++) {
                float qk = c[r];
                float e = __expf(qk * 0.125f);
                float tt = (2.f * qk - qn_r[r] - knp) * is_r[r];
                float rb = fminf(__expf(tt), 1.0f);
                es_p[r] += e; rs_p[r] += rb;
                PeW[(kq * 4 + r) * 72 + jtl * 16 + ml] = f2bf(e);
                PrW[(kq * 4 + r) * 72 + jtl * 16 + ml] = f2bf(rb);
            }
        }
        // (no barrier: P round-trip is wave-local)

#pragma unroll
        for (int jcl = 0; jcl < 2; jcl++) {
            bf16x8 pa_e = *(const bf16x8*)&PeW[ml * 72 + jcl * 32 + kq * 8];
            bf16x8 pa_r = *(const bf16x8*)&PrW[ml * 72 + jcl * 32 + kq * 8];
#pragma unroll
            for (int dt = 0; dt < 4; dt++) {
                bf16x8 bv = *(const bf16x8*)&Vit[(jcl * 4 + dt) * 512 + lane * 8];
                Oe[dt] = __builtin_amdgcn_mfma_f32_16x16x32_bf16(pa_e, bv, Oe[dt], 0, 0, 0);
                Or[dt] = __builtin_amdgcn_mfma_f32_16x16x32_bf16(pa_r, bv, Or[dt], 0, 0, 0);
            }
        }
    }

    // per-wave es/rs row sums (sum across ml within each kq group)
#pragma unroll
    for (int off = 1; off <= 8; off <<= 1) {
#pragma unroll
        for (int r = 0; r < 4; r++) {
            es_p[r] += __shfl_xor(es_p[r], off);
            rs_p[r] += __shfl_xor(rs_p[r], off);
        }
    }

    // cross-quarter combine in LDS (Pe/Pr region dead after the loop).
    // Element-major layout: cb[e*192 + (wp-1)*64 + lane] -> each LDS
    // instruction has 64 consecutive lanes -> conflict-free.
    __syncthreads();                     // all waves past their last P read
    float* cb = (float*)Pbuf;
    if (wp) {
        float* cl = cb + (wp - 1) * 64 + lane;
#pragma unroll
        for (int dt = 0; dt < 4; dt++)
#pragma unroll
            for (int r = 0; r < 4; r++) {
                cl[(dt * 4 + r) * 192] = Oe[dt][r];
                cl[(16 + dt * 4 + r) * 192] = Or[dt][r];
            }
        if (ml == 0) {
#pragma unroll
            for (int r = 0; r < 4; r++) {
                esx[wp - 1][kq * 4 + r] = es_p[r];
                rsx[wp - 1][kq * 4 + r] = rs_p[r];
            }
        }
    }
    __syncthreads();
    if (wp == 0) {
        float p = pond[0];
        float sv = 1.0f / (1.0f + __expf(-p));
        float p0 = 1.0f - sv, p1 = sv;
        float blendinv = 1.0f / (p0 + p1 + 1e-7f);
        float we[4], wr[4];
#pragma unroll
        for (int r = 0; r < 4; r++) {
            float es = es_p[r] + esx[0][kq * 4 + r] + esx[1][kq * 4 + r] + esx[2][kq * 4 + r];
            float rs = rs_p[r] + rsx[0][kq * 4 + r] + rsx[1][kq * 4 + r] + rsx[2][kq * 4 + r];
            we[r] = p0 * blendinv / es;
            wr[r] = p1 * blendinv / fmaxf(rs, 1e-8f);
        }
#pragma unroll
        for (int dt = 0; dt < 4; dt++) {
#pragma unroll
            for (int r = 0; r < 4; r++) {
                int e0 = dt * 4 + r;
                float oe = Oe[dt][r] + cb[e0 * 192 + lane] + cb[e0 * 192 + 64 + lane]
                         + cb[e0 * 192 + 128 + lane];
                float orr = Or[dt][r] + cb[(16 + e0) * 192 + lane] + cb[(16 + e0) * 192 + 64 + lane]
                          + cb[(16 + e0) * 192 + 128 + lane];
                float v = oe * we[r] + orr * wr[r];
                int token = b * S_LEN + qt * 16 + kq * 4 + r;
                vals[(size_t)token * 768 + h * 64 + dt * 16 + ml] = f2bf(v);
            }
        }
    }
}

// ---------------- launcher -------------------------------------------------

extern "C" void kernel_launch(void* const* d_in, const int* in_sizes, int n_in,
                              void* d_out, int out_size, void* d_ws, size_t ws_size,
                              hipStream_t stream) {
    const float* x     = (const float*)d_in[0];
    const float* ln1_w = (const float*)d_in[1];
    const float* ln1_b = (const float*)d_in[2];
    const float* Wq    = (const float*)d_in[3];
    const float* bq    = (const float*)d_in[4];
    const float* Wk    = (const float*)d_in[5];
    const float* bk    = (const float*)d_in[6];
    const float* Wv    = (const float*)d_in[7];
    const float* bv    = (const float*)d_in[8];
    const float* Wo    = (const float*)d_in[9];
    const float* bo    = (const float*)d_in[10];
    const float* pond  = (const float*)d_in[11];
    const float* ln2_w = (const float*)d_in[12];
    const float* ln2_b = (const float*)d_in[13];
    const float* fc1_W = (const float*)d_in[14];
    const float* fc1_b = (const float*)d_in[15];
    const float* vqc_W = (const float*)d_in[16];
    const float* vqc_b = (const float*)d_in[17];
    const float* fc2_W = (const float*)d_in[18];
    const float* fc2_b = (const float*)d_in[19];
    float* out = (float*)d_out;

    char* p = (char*)d_ws;
    short* Qb   = (short*)p;  p += (size_t)2048 * 768 * 2;
    short* Kfb  = (short*)p;  p += (size_t)2048 * 768 * 2;
    short* Vfb  = (short*)p;  p += (size_t)2048 * 768 * 2;
    float* x2   = (float*)p;  p += (size_t)2048 * 768 * 4;
    float* bqkv = (float*)p;  p += 2304 * 4;
    short* actb = (short*)p;  p += (size_t)2048 * 768 * 2;
    short* g    = (short*)p;  p += (size_t)2048 * 3072 * 2;
    short* Avqc = (short*)p;  p += (size_t)8192 * 768 * 2;
    short* partb = (short*)p; p += (size_t)4 * 2048 * 768 * 2;   // 12.6 MB split-K partials
    short* wreg = (short*)p;  p += (size_t)5900544 * 2;
    short* Wqkvb = wreg;
    short* Wob   = wreg + 1769472;
    short* fc1b  = wreg + 2359296;
    short* vqcb  = wreg + 2951424;
    short* fc2b  = wreg + 3541248;

    dim3 blk(256);
    const size_t SP = (size_t)2048 * 768;

    // 0. preamble: ln1 + bias concat + weight conversion (one grid)
    preamble<<<7812, blk, 0, stream>>>(Wq, Wk, Wv, Wo, fc1_W, vqc_W, fc2_W, wreg,
                                       bq, bk, bv, bqkv, x, ln1_w, ln1_b, actb);
    // 1. fused QKV projection (direct, dbuf, 576 blocks)
    gemm_bf16<3, 64><<<dim3(18, 32, 1), blk, 0, stream>>>(actb, 768, Wqkvb, 768, bqkv,
                                                          Qb, 768, 0, Kfb, Vfb, 2304, 768, 0);
    // 2. MFMA attention, 4-way KV split, 16 q-rows/block, direct-L2 reads,
    //    1536 blocks = 6/CU exact (24 waves/CU), XCD-affinity swizzled
    attn_mfma<<<1536, blk, 0, stream>>>(Qb, Kfb, Vfb, pond, actb);
    // 3. Wo split-K x4 (768 blocks = 3/CU)
    gemm_bf16<5, 64><<<dim3(6, 32, 4), blk, 0, stream>>>(actb, 768, Wob, 768, nullptr,
                                                         partb, 768, SP,
                                                         nullptr, nullptr, 768, 192, 0);
    // 4. reduce + bo + residual(x) -> x2 fp32, fused ln2 -> actb
    reduce_wo_ln<<<2048, blk, 0, stream>>>(partb, bo, x, ln2_w, ln2_b, x2, actb);
    // 5. fc1 split-K x4, cols 0..767 only (768 blocks = 3/CU exact)
    gemm_bf16<5, 64><<<dim3(6, 32, 4), blk, 0, stream>>>(actb, 768, fc1b, 768, nullptr,
                                                         partb, 768, SP,
                                                         nullptr, nullptr, 768, 192, 0);
    // 6. reduce + bias + cols 768..770 dots + expand -> Avqc [8192][768]
    reduce_fc1_expand<<<2048, blk, 0, stream>>>(partb, fc1_b, actb, fc1b + 768 * 768, Avqc);
    // 7. vqc (direct) + bias + gelu + transpose scatter (768 blocks = 3/CU)
    gemm_bf16<2, 64><<<dim3(6, 128, 1), blk, 0, stream>>>(Avqc, 768, vqcb, 768, vqc_b,
                                                          g, 3072, 0, nullptr, nullptr, 768, 768, 1);
    // 8. fc2 split-K x4 (768 blocks = 3/CU)
    gemm_bf16<5, 64><<<dim3(6, 32, 4), blk, 0, stream>>>(g, 3072, fc2b, 3072, nullptr,
                                                         partb, 768, SP,
                                                         nullptr, nullptr, 768, 768, 0);
    // 9. reduce + bias + residual(x2) -> out fp32
    reduce_fc2<<<1536, blk, 0, stream>>>(partb, fc2_b, x2, out);
}

// Round 4
// 150.328 us; speedup vs baseline: 1.1951x; 1.0575x over previous
//
#include <hip/hip_runtime.h>
#include <math.h>

#define E_DIM 768
#define S_LEN 1024
#define B_SZ 2
#define H_CNT 12
#define D_HEAD 64
#define M_DIM 768
#define Q_STRIDE 4
#define N_FC1 771            // only M+Q-1 columns of fc1 are consumed

typedef __attribute__((ext_vector_type(8))) short bf16x8;
typedef __attribute__((ext_vector_type(4))) float f32x4;

#define AS1 __attribute__((address_space(1)))
#define AS3 __attribute__((address_space(3)))

__device__ __forceinline__ void gld_lds16(void* lds, const void* g) {
    __builtin_amdgcn_global_load_lds((const AS1 void*)g, (AS3 void*)lds, 16, 0, 0);
}

__device__ __forceinline__ short f2bf(float f) {
    unsigned u = __float_as_uint(f);
    unsigned r = (u + 0x7fffu + ((u >> 16) & 1u)) >> 16;
    return (short)r;
}

__device__ __forceinline__ float bf2f(short s) {
    return __uint_as_float(((unsigned)(unsigned short)s) << 16);
}

// ---------------- block reduction helper (256 threads, 4 waves) ------------

__device__ __forceinline__ float block_reduce_sum(float v, volatile float* red) {
#pragma unroll
    for (int off = 32; off > 0; off >>= 1) v += __shfl_xor(v, off);
    __syncthreads();
    if ((threadIdx.x & 63) == 0) red[threadIdx.x >> 6] = v;
    __syncthreads();
    return red[0] + red[1] + red[2] + red[3];
}

// ------------- preamble: ln1 + bias concat + weight conversion, one grid ---

__global__ __launch_bounds__(256) void preamble(
        const float* __restrict__ Wq, const float* __restrict__ Wk,
        const float* __restrict__ Wv, const float* __restrict__ Wo,
        const float* __restrict__ fc1W, const float* __restrict__ vqcW,
        const float* __restrict__ fc2W, short* __restrict__ dst,
        const float* __restrict__ bq, const float* __restrict__ bk,
        const float* __restrict__ bv, float* __restrict__ bqkv,
        const float* __restrict__ x, const float* __restrict__ ln1_w,
        const float* __restrict__ ln1_b, short* __restrict__ actb) {
    __shared__ float red[4];
    int tid = threadIdx.x;
    if (blockIdx.x < 2048) {          // ln1
        int row = blockIdx.x;
        const float* xr = x + (size_t)row * E_DIM;
        float v0 = xr[tid], v1 = xr[tid + 256], v2 = xr[tid + 512];
        float s = block_reduce_sum(v0 + v1 + v2, red);
        float mu = s * (1.0f / E_DIM);
        float d0 = v0 - mu, d1 = v1 - mu, d2 = v2 - mu;
        float var = block_reduce_sum(d0 * d0 + d1 * d1 + d2 * d2, red) * (1.0f / E_DIM);
        float rs = rsqrtf(var + 1e-5f);
        short* orow = actb + (size_t)row * E_DIM;
        orow[tid]       = f2bf(d0 * rs * ln1_w[tid]       + ln1_b[tid]);
        orow[tid + 256] = f2bf(d1 * rs * ln1_w[tid + 256] + ln1_b[tid + 256]);
        orow[tid + 512] = f2bf(d2 * rs * ln1_w[tid + 512] + ln1_b[tid + 512]);
        return;
    }
    if (blockIdx.x == 2048) {         // bias concat
#pragma unroll
        for (int u = 0; u < 9; u++) {
            int i = tid + u * 256;
            float v = (i < 768) ? bq[i] : (i < 1536) ? bk[i - 768] : bv[i - 1536];
            bqkv[i] = v;
        }
        return;
    }
    int t = (blockIdx.x - 2049) * 256 + tid;      // float4 index
    if (t >= 1475136) return;                     // 5900544 / 4
    int e = t * 4;
    const float* src; int off;
    if      (e < 589824)  { src = Wq;   off = e; }
    else if (e < 1179648) { src = Wk;   off = e - 589824; }
    else if (e < 1769472) { src = Wv;   off = e - 1179648; }
    else if (e < 2359296) { src = Wo;   off = e - 1769472; }
    else if (e < 2951424) { src = fc1W; off = e - 2359296; }
    else if (e < 3541248) { src = vqcW; off = e - 2951424; }
    else                  { src = fc2W; off = e - 3541248; }
    float4 v = *(const float4*)(src + off);
    short4 o = make_short4(f2bf(v.x), f2bf(v.y), f2bf(v.z), f2bf(v.w));
    *(short4*)(dst + e) = o;
}

// ---------------- bf16 MFMA NT GEMM (BK=64, double-buffered, MR-templated) -
// MR x 128 tile, BK=64 (two MRx32 sub-slabs), double-buffered (one barrier
// per iteration). LDS 48 KB at MR=64 -> 3 blocks/CU, matching 768-block
// balanced grids (R10). R5/R6 lesson: runtime-branch epilogues flip the
// allocator into a 68-VGPR accumulator-spill regime; keep OUTMODE a
// template + launch_bounds(256,2). XOR k-slot swizzle -> 2-way alias (free).
// OUTMODE: 2 = bias+GELU+bf16 transpose-scatter (vqc); 3 = QKV split
//          (+ fp32 q/k row-norm side outputs qnG/knG for the attention's
//          RBF term -- R16: hoists the per-iteration knp recompute out of
//          the attention inner loop); 5 = bf16 partial at outp + z*spitch.

template <int OUTMODE, int MR>
__global__ __launch_bounds__(256, 2) void gemm_bf16(
        const short* __restrict__ A, int lda,
        const short* __restrict__ W, int ldw,
        const float* __restrict__ bias,
        void* __restrict__ outp, int ldo, size_t spitch,
        short* __restrict__ Kfp, short* __restrict__ Vfp,
        int N, int klen, int dogelu,
        float* __restrict__ qnG, float* __restrict__ knG) {
    constexpr int MI = MR / 32;
    constexpr int AH = MR * 32;
    constexpr int NA = MR / 64;
    constexpr int ASL = 2 * AH;
    __shared__ short At[2 * ASL];
    __shared__ short Bt[2 * 8192];
    const int tid = threadIdx.x;
    const int lane = tid & 63;
    const int wave = tid >> 6;
    const int wr = (wave >> 1) * (MI * 16);
    const int wc = (wave & 1) * 64;
    const int ml = lane & 15;
    const int kq = lane >> 4;
    const int row0 = blockIdx.y * MR;
    const int col0 = blockIdx.x * 128;
    const int kbase = blockIdx.z * klen;

    const short* Ag[NA]; int aoff[NA];
#pragma unroll
    for (int u = 0; u < NA; u++) {
        int c = tid + u * 256;
        int am = c >> 2, ak = ((c & 3) ^ ((am >> 1) & 3)) * 8;
        Ag[u] = A + (size_t)(row0 + am) * lda + ak + kbase;
        aoff[u] = c * 8;
    }
    const int c0 = tid, c1 = tid + 256;
    const int bm0 = c0 >> 2, bk0 = (((c0 & 3) ^ ((bm0 >> 1) & 3))) * 8;
    const int bm1 = c1 >> 2, bk1 = (((c1 & 3) ^ ((bm1 >> 1) & 3))) * 8;
    int wrow0 = col0 + bm0; if (wrow0 > N - 1) wrow0 = N - 1;
    int wrow1 = col0 + bm1; if (wrow1 > N - 1) wrow1 = N - 1;
    const short* Wg0 = W + (size_t)wrow0 * ldw + bk0 + kbase;
    const short* Wg1 = W + (size_t)wrow1 * ldw + bk1 + kbase;

    const int kxor = (kq ^ ((ml >> 1) & 3)) * 8;

    f32x4 acc[MI][4];
#pragma unroll
    for (int i = 0; i < MI; i++)
#pragma unroll
        for (int j = 0; j < 4; j++) acc[i][j] = {0.f, 0.f, 0.f, 0.f};

    auto stage = [&](int buf, int k0) {
        short* Ab = At + buf * ASL;
        short* Bb = Bt + buf * 8192;
#pragma unroll
        for (int u = 0; u < NA; u++) {
            gld_lds16(Ab + aoff[u], Ag[u] + k0);
            gld_lds16(Ab + AH + aoff[u], Ag[u] + k0 + 32);
        }
        gld_lds16(Bb + c0 * 8, Wg0 + k0);
        gld_lds16(Bb + c1 * 8, Wg1 + k0);
        gld_lds16(Bb + 4096 + c0 * 8, Wg0 + k0 + 32);
        gld_lds16(Bb + 4096 + c1 * 8, Wg1 + k0 + 32);
    };

    stage(0, 0);
    int cur = 0;
    for (int k0 = 0; k0 < klen; k0 += 64) {
        __syncthreads();
        if (k0 + 64 < klen) stage(cur ^ 1, k0 + 64);
        const short* Ac = At + cur * ASL;
        const short* Bc = Bt + cur * 8192;
#pragma unroll
        for (int half = 0; half < 2; half++) {
            const short* Ah = Ac + half * AH;
            const short* Bh = Bc + half * 4096;
            bf16x8 af[MI], bfr[4];
#pragma unroll
            for (int i = 0; i < MI; i++)
                af[i] = *(const bf16x8*)&Ah[(wr + i * 16 + ml) * 32 + kxor];
#pragma unroll
            for (int j = 0; j < 4; j++)
                bfr[j] = *(const bf16x8*)&Bh[(wc + j * 16 + ml) * 32 + kxor];
#pragma unroll
            for (int i = 0; i < MI; i++)
#pragma unroll
                for (int j = 0; j < 4; j++)
                    acc[i][j] = __builtin_amdgcn_mfma_f32_16x16x32_bf16(af[i], bfr[j], acc[i][j], 0, 0, 0);
        }
        cur ^= 1;
    }

    // epilogue: C/D layout col = lane&15, row = (lane>>4)*4 + reg
    float sq[MI][4];
    if constexpr (OUTMODE == 3) {
#pragma unroll
        for (int i = 0; i < MI; i++)
#pragma unroll
            for (int rr = 0; rr < 4; rr++) sq[i][rr] = 0.f;
    }
#pragma unroll
    for (int i = 0; i < MI; i++) {
#pragma unroll
        for (int j = 0; j < 4; j++) {
#pragma unroll
            for (int rr = 0; rr < 4; rr++) {
                int r = row0 + wr + i * 16 + kq * 4 + rr;
                int c = col0 + wc + j * 16 + ml;
                if (c < N) {
                    float v = acc[i][j][rr];
                    if (OUTMODE < 4) v += bias[c];
                    if (OUTMODE == 2 && dogelu)
                        v = 0.5f * v * (1.0f + erff(v * 0.70710678118654752f));
                    if (OUTMODE == 2) {
                        ((short*)outp)[(size_t)(r >> 2) * ldo + c * 4 + (r & 3)] = f2bf(v);
                    } else if (OUTMODE == 5) {
                        ((short*)outp)[blockIdx.z * spitch + (size_t)r * ldo + c] = f2bf(v);
                    } else if (OUTMODE == 3) {
                        sq[i][rr] += v * v;
                        int s = r & 1023, bb = r >> 10;
                        if (c < 768) {
                            ((short*)outp)[(size_t)r * 768 + c] = f2bf(v);
                        } else if (c < 1536) {
                            int df = c - 768; int hh = df >> 6, d = df & 63;
                            int bh2 = bb * 12 + hh;
                            size_t idx = ((size_t)(bh2 * 64 + (s >> 4)) * 2 + (d >> 5)) * 512
                                       + (size_t)((d >> 3) & 3) * 128 + (size_t)(s & 15) * 8 + (d & 7);
                            Kfp[idx] = f2bf(v);
                        } else {
                            int df = c - 1536; int hh = df >> 6, d = df & 63;
                            int bh2 = bb * 12 + hh;
                            size_t idx = ((size_t)(bh2 * 32 + (s >> 5))) * 2048
                                       + (size_t)(d >> 4) * 512 + (size_t)((s >> 3) & 3) * 128
                                       + (size_t)(d & 15) * 8 + (s & 7);
                            Vfp[idx] = f2bf(v);
                        }
                    }
                }
            }
        }
    }

    if constexpr (OUTMODE == 3) {
        // fp32 row-norm side outputs. Each wave's 64-col span [cb, cb+64)
        // is exactly one (matrix, head) group (col0, wc multiples of 64).
        int cb = col0 + wc;
        if (cb < 1536) {
            float* dst = (cb < 768) ? qnG : knG;
            int hh = ((cb < 768) ? cb : cb - 768) >> 6;
#pragma unroll
            for (int i = 0; i < MI; i++) {
#pragma unroll
                for (int rr = 0; rr < 4; rr++) {
                    float s = sq[i][rr];
                    s += __shfl_xor(s, 1);
                    s += __shfl_xor(s, 2);
                    s += __shfl_xor(s, 4);
                    s += __shfl_xor(s, 8);
                    if (ml == 0) {
                        int r = row0 + wr + i * 16 + kq * 4 + rr;
                        int bb = r >> 10, sidx = r & 1023;
                        dst[(size_t)(bb * 12 + hh) * 1024 + sidx] = s;
                    }
                }
            }
        }
    }
}

// ---------------- split-K reduce kernels -----------------------------------

// Wo partials (4, bf16) + bo + residual x -> x2 fp32, then LN(ln2) -> y bf16
__global__ __launch_bounds__(256) void reduce_wo_ln(
        const short* __restrict__ part, const float* __restrict__ bo,
        const float* __restrict__ x, const float* __restrict__ w,
        const float* __restrict__ bvec, float* __restrict__ x2,
        short* __restrict__ y) {
    __shared__ float red[4];
    int row = blockIdx.x, tid = threadIdx.x;
    const size_t SP = (size_t)2048 * 768;
    const short* pr = part + (size_t)row * 768;
    const float* xr = x + (size_t)row * 768;
    float* x2r = x2 + (size_t)row * 768;
    float v[3];
#pragma unroll
    for (int u = 0; u < 3; u++) {
        int c = tid + u * 256;
        float s = bo[c] + xr[c];
#pragma unroll
        for (int z = 0; z < 4; z++) s += bf2f(pr[z * SP + c]);
        v[u] = s; x2r[c] = s;
    }
    float s = block_reduce_sum(v[0] + v[1] + v[2], red);
    float mu = s * (1.0f / 768.f);
    float d0 = v[0] - mu, d1 = v[1] - mu, d2 = v[2] - mu;
    float var = block_reduce_sum(d0 * d0 + d1 * d1 + d2 * d2, red) * (1.0f / 768.f);
    float rs = rsqrtf(var + 1e-5f);
    short* orow = y + (size_t)row * 768;
    orow[tid]       = f2bf(d0 * rs * w[tid]       + bvec[tid]);
    orow[tid + 256] = f2bf(d1 * rs * w[tid + 256] + bvec[tid + 256]);
    orow[tid + 512] = f2bf(d2 * rs * w[tid + 512] + bvec[tid + 512]);
}

// fc1 partials (4, bf16 [2048][768], cols 0..767) + bias -> expanded slices.
// Cols 768..770 computed here as block-reduced dots y[r].fc1_W[768+k] so the
// fc1 GEMM runs an exact 768-block grid. Avqc[(r*4+q)][m] = h1[r][m+q].
__global__ __launch_bounds__(256) void reduce_fc1_expand(
        const short* __restrict__ part, const float* __restrict__ b,
        const short* __restrict__ y, const short* __restrict__ w768,
        short* __restrict__ Avqc) {
    __shared__ float row[772];
    __shared__ float red[4];
    int r = blockIdx.x, tid = threadIdx.x;
    const size_t SP = (size_t)2048 * 768;
    const short* pr = part + (size_t)r * 768;
#pragma unroll
    for (int u = 0; u < 3; u++) {
        int c = tid + u * 256;
        float s = b[c];
#pragma unroll
        for (int z = 0; z < 4; z++) s += bf2f(pr[z * SP + c]);
        row[c] = s;
    }
    const short* yr = y + (size_t)r * 768;
    float y0 = bf2f(yr[tid]), y1 = bf2f(yr[tid + 256]), y2 = bf2f(yr[tid + 512]);
#pragma unroll
    for (int k = 0; k < 3; k++) {
        const short* wk = w768 + k * 768;
        float s = y0 * bf2f(wk[tid]) + y1 * bf2f(wk[tid + 256]) + y2 * bf2f(wk[tid + 512]);
        s = block_reduce_sum(s, red);
        if (tid == 0) row[768 + k] = s + b[768 + k];
    }
    __syncthreads();
#pragma unroll
    for (int q = 0; q < 4; q++) {
        short* orow = Avqc + (size_t)(r * 4 + q) * 768;
#pragma unroll
        for (int u = 0; u < 3; u++) {
            int m = tid + u * 256;
            orow[m] = f2bf(row[m + q]);
        }
    }
}

// fc2 partials (4, bf16) + bias + residual x2 -> out fp32
__global__ __launch_bounds__(256) void reduce_fc2(
        const short* __restrict__ part, const float* __restrict__ b,
        const float* __restrict__ x2, float* __restrict__ out) {
    int t = blockIdx.x * 256 + threadIdx.x;
    int row = t / 192;
    int c = (t - row * 192) * 4;
    size_t off = (size_t)row * 768 + c;
    const size_t SP = (size_t)2048 * 768;
    float4 bb = *(const float4*)(b + c);
    float4 xx = *(const float4*)(x2 + off);
    float o0 = bb.x + xx.x, o1 = bb.y + xx.y, o2 = bb.z + xx.z, o3 = bb.w + xx.w;
#pragma unroll
    for (int z = 0; z < 4; z++) {
        short4 v = *(const short4*)(part + z * SP + off);
        o0 += bf2f(v.x); o1 += bf2f(v.y); o2 += bf2f(v.z); o3 += bf2f(v.w);
    }
    float4 o = make_float4(o0, o1, o2, o3);
    *(float4*)(out + off) = o;
}

// ---------------- MFMA fused attention, INTRA-BLOCK KV-split ---------------
// R16: reverted to the R12/R0 LDS-staged structure -- measured ladder:
// staged 41.1 us < direct-L2 46.8/47.0 us (staging is shared by 2 q-waves
// and replaces ~200cy L2 latency on the critical path with ~12cy ds_reads;
// the "L2-fits so don't stage" heuristic LOST here). Changes vs R0:
//  (a) q/k row-norms are no longer recomputed in-loop from bf16 frags
//      (128 VALU + 8 shuffles per iteration, ~25% of VALU, on the serial
//      QK->softmax chain) -- they come from fp32 qnG/knG tables written by
//      the QKV GEMM epilogue. kn loads are issued with the stage, so the
//      barrier's vmcnt drain hides them.
//  (b) bijective XCD swizzle (768 = 8 x 96): all 32 blocks of one (b,h)
//      share one XCD's L2 -> KV fetched from HBM once per XCD.

__global__ __launch_bounds__(256) void attn_mfma(
        const short* __restrict__ Qb,    // [2048][768] bf16
        const short* __restrict__ Kf,    // frag-major
        const short* __restrict__ Vf,    // frag-major
        const float* __restrict__ pond,
        const float* __restrict__ qnG,   // [24][1024] fp32 |q|^2
        const float* __restrict__ knG,   // [24][1024] fp32 |k|^2
        short* __restrict__ vals) {      // [2048][768] bf16
    __shared__ __align__(16) short Kt[2 * 4096];   // [wp][tile]; reused as combine buf
    __shared__ __align__(16) short Vt[2 * 4096];
    __shared__ float esx[2][16], rsx[2][16];
    __shared__ __align__(16) short Pe[4 * 16 * 72];
    __shared__ __align__(16) short Pr[4 * 16 * 72];

    const int tid = threadIdx.x;
    const int lane = tid & 63;
    const int wave = tid >> 6;
    const int wq = wave & 1;       // q sub-tile
    const int wp = wave >> 1;      // KV half
    const int ml = lane & 15;
    const int kq = lane >> 4;

    // XCD-affinity swizzle (768 = 8 XCDs x 96 -> bijective)
    const int fid = blockIdx.x;
    const int w = (fid & 7) * 96 + (fid >> 3);
    const int qt2 = w & 31;
    const int bh = w >> 5;          // 0..23
    const int b = (bh >= 12) ? 1 : 0;
    const int h = bh - b * 12;

    const int qrow = b * S_LEN + qt2 * 32 + wq * 16 + ml;
    const short* qp = Qb + (size_t)qrow * 768 + h * 64 + kq * 8;
    bf16x8 aq0 = *(const bf16x8*)qp;
    bf16x8 aq1 = *(const bf16x8*)(qp + 32);

    // fp32 q-norms from the QKV epilogue (rows kq*4+r of this wave's tile)
    const float* qnB = qnG + (size_t)bh * 1024 + qt2 * 32 + wq * 16;
    float qn_r[4], is_r[4];
#pragma unroll
    for (int r = 0; r < 4; r++) {
        qn_r[r] = qnB[kq * 4 + r];
        is_r[r] = 1.0f / fminf(fmaxf(qn_r[r], 1e-8f), 1e4f);
    }
    const float* knB = knG + (size_t)bh * 1024;

    f32x4 Oe[4], Or[4];
#pragma unroll
    for (int dt = 0; dt < 4; dt++) { Oe[dt] = {0.f,0.f,0.f,0.f}; Or[dt] = {0.f,0.f,0.f,0.f}; }
    float es_p[4] = {0.f,0.f,0.f,0.f}, rs_p[4] = {0.f,0.f,0.f,0.f};

    const short* KfB = Kf + (size_t)bh * 65536;
    const short* VfB = Vf + (size_t)bh * 65536;
    short* PeW = Pe + wave * 1152;
    short* PrW = Pr + wave * 1152;
    const short* KtW = Kt + wp * 4096;
    const short* VtW = Vt + wp * 4096;

    for (int it = 0; it < 8; it++) {
        __syncthreads();   // all waves done reading prior tiles
        {
            const short* sk0 = KfB + it * 4096 + tid * 8;
            gld_lds16(Kt + tid * 8, sk0);
            gld_lds16(Kt + 2048 + tid * 8, sk0 + 2048);
            const short* sk1 = KfB + (it + 8) * 4096 + tid * 8;
            gld_lds16(Kt + 4096 + tid * 8, sk1);
            gld_lds16(Kt + 6144 + tid * 8, sk1 + 2048);
            const short* sv0 = VfB + it * 4096 + tid * 8;
            gld_lds16(Vt + tid * 8, sv0);
            gld_lds16(Vt + 2048 + tid * 8, sv0 + 2048);
            const short* sv1 = VfB + (it + 8) * 4096 + tid * 8;
            gld_lds16(Vt + 4096 + tid * 8, sv1);
            gld_lds16(Vt + 6144 + tid * 8, sv1 + 2048);
        }
        // k-norms for this wave's tile; land under the barrier's vmcnt drain
        float knt[4];
        {
            const float* knI = knB + (it + 8 * wp) * 64 + ml;
#pragma unroll
            for (int jtl = 0; jtl < 4; jtl++) knt[jtl] = knI[jtl * 16];
        }
        __syncthreads();   // tiles resident

#pragma unroll
        for (int jtl = 0; jtl < 4; jtl++) {
            bf16x8 bk0 = *(const bf16x8*)&KtW[(jtl * 2 + 0) * 512 + lane * 8];
            bf16x8 bk1 = *(const bf16x8*)&KtW[(jtl * 2 + 1) * 512 + lane * 8];
            f32x4 c = {0.f,0.f,0.f,0.f};
            c = __builtin_amdgcn_mfma_f32_16x16x32_bf16(aq0, bk0, c, 0, 0, 0);
            c = __builtin_amdgcn_mfma_f32_16x16x32_bf16(aq1, bk1, c, 0, 0, 0);
#pragma unroll
            for (int r = 0; r < 4; r++) {
                float qk = c[r];
                float e = __expf(qk * 0.125f);
                float tt = (2.f * qk - qn_r[r] - knt[jtl]) * is_r[r];
                float rb = fminf(__expf(tt), 1.0f);
                es_p[r] += e; rs_p[r] += rb;
                PeW[(kq * 4 + r) * 72 + jtl * 16 + ml] = f2bf(e);
                PrW[(kq * 4 + r) * 72 + jtl * 16 + ml] = f2bf(rb);
            }
        }
        // (no barrier: P round-trip is wave-local)

#pragma unroll
        for (int jcl = 0; jcl < 2; jcl++) {
            bf16x8 pa_e = *(const bf16x8*)&PeW[ml * 72 + jcl * 32 + kq * 8];
            bf16x8 pa_r = *(const bf16x8*)&PrW[ml * 72 + jcl * 32 + kq * 8];
#pragma unroll
            for (int dt = 0; dt < 4; dt++) {
                bf16x8 bv = *(const bf16x8*)&VtW[(jcl * 4 + dt) * 512 + lane * 8];
                Oe[dt] = __builtin_amdgcn_mfma_f32_16x16x32_bf16(pa_e, bv, Oe[dt], 0, 0, 0);
                Or[dt] = __builtin_amdgcn_mfma_f32_16x16x32_bf16(pa_r, bv, Or[dt], 0, 0, 0);
            }
        }
    }

    // per-wave es/rs row sums
#pragma unroll
    for (int off = 1; off <= 8; off <<= 1) {
#pragma unroll
        for (int r = 0; r < 4; r++) {
            es_p[r] += __shfl_xor(es_p[r], off);
            rs_p[r] += __shfl_xor(rs_p[r], off);
        }
    }

    // cross-half combine in LDS (Kt region is dead after the loop)
    __syncthreads();                     // everyone past the last QK read of Kt
    float* cb = (float*)Kt;              // 16 KB: [wq*64+lane][32]
    if (wp == 1) {
        float* cl = cb + (size_t)(wq * 64 + lane) * 32;
#pragma unroll
        for (int dt = 0; dt < 4; dt++)
#pragma unroll
            for (int r = 0; r < 4; r++) {
                cl[dt * 4 + r] = Oe[dt][r];
                cl[16 + dt * 4 + r] = Or[dt][r];
            }
        if (ml == 0) {
#pragma unroll
            for (int r = 0; r < 4; r++) {
                esx[wq][kq * 4 + r] = es_p[r];
                rsx[wq][kq * 4 + r] = rs_p[r];
            }
        }
    }
    __syncthreads();
    if (wp == 0) {
        float p = pond[0];
        float sv = 1.0f / (1.0f + __expf(-p));
        float p0 = 1.0f - sv, p1 = sv;
        float blendinv = 1.0f / (p0 + p1 + 1e-7f);
        const float* cl = cb + (size_t)(wq * 64 + lane) * 32;
        float we[4], wr[4];
#pragma unroll
        for (int r = 0; r < 4; r++) {
            float es = es_p[r] + esx[wq][kq * 4 + r];
            float rs = rs_p[r] + rsx[wq][kq * 4 + r];
            we[r] = p0 * blendinv / es;
            wr[r] = p1 * blendinv / fmaxf(rs, 1e-8f);
        }
#pragma unroll
        for (int dt = 0; dt < 4; dt++) {
#pragma unroll
            for (int r = 0; r < 4; r++) {
                float oe = Oe[dt][r] + cl[dt * 4 + r];
                float orr = Or[dt][r] + cl[16 + dt * 4 + r];
                float v = oe * we[r] + orr * wr[r];
                int token = b * S_LEN + qt2 * 32 + wq * 16 + kq * 4 + r;
                vals[(size_t)token * 768 + h * 64 + dt * 16 + ml] = f2bf(v);
            }
        }
    }
}

// ---------------- launcher -------------------------------------------------

extern "C" void kernel_launch(void* const* d_in, const int* in_sizes, int n_in,
                              void* d_out, int out_size, void* d_ws, size_t ws_size,
                              hipStream_t stream) {
    const float* x     = (const float*)d_in[0];
    const float* ln1_w = (const float*)d_in[1];
    const float* ln1_b = (const float*)d_in[2];
    const float* Wq    = (const float*)d_in[3];
    const float* bq    = (const float*)d_in[4];
    const float* Wk    = (const float*)d_in[5];
    const float* bk    = (const float*)d_in[6];
    const float* Wv    = (const float*)d_in[7];
    const float* bv    = (const float*)d_in[8];
    const float* Wo    = (const float*)d_in[9];
    const float* bo    = (const float*)d_in[10];
    const float* pond  = (const float*)d_in[11];
    const float* ln2_w = (const float*)d_in[12];
    const float* ln2_b = (const float*)d_in[13];
    const float* fc1_W = (const float*)d_in[14];
    const float* fc1_b = (const float*)d_in[15];
    const float* vqc_W = (const float*)d_in[16];
    const float* vqc_b = (const float*)d_in[17];
    const float* fc2_W = (const float*)d_in[18];
    const float* fc2_b = (const float*)d_in[19];
    float* out = (float*)d_out;

    char* p = (char*)d_ws;
    short* Qb   = (short*)p;  p += (size_t)2048 * 768 * 2;
    short* Kfb  = (short*)p;  p += (size_t)2048 * 768 * 2;
    short* Vfb  = (short*)p;  p += (size_t)2048 * 768 * 2;
    float* x2   = (float*)p;  p += (size_t)2048 * 768 * 4;
    float* bqkv = (float*)p;  p += 2304 * 4;
    float* qnG  = (float*)p;  p += (size_t)24 * 1024 * 4;
    float* knG  = (float*)p;  p += (size_t)24 * 1024 * 4;
    short* actb = (short*)p;  p += (size_t)2048 * 768 * 2;
    short* g    = (short*)p;  p += (size_t)2048 * 3072 * 2;
    short* Avqc = (short*)p;  p += (size_t)8192 * 768 * 2;
    short* partb = (short*)p; p += (size_t)4 * 2048 * 768 * 2;   // 12.6 MB split-K partials
    short* wreg = (short*)p;  p += (size_t)5900544 * 2;
    short* Wqkvb = wreg;
    short* Wob   = wreg + 1769472;
    short* fc1b  = wreg + 2359296;
    short* vqcb  = wreg + 2951424;
    short* fc2b  = wreg + 3541248;

    dim3 blk(256);
    const size_t SP = (size_t)2048 * 768;

    // 0. preamble: ln1 + bias concat + weight conversion (one grid)
    preamble<<<7812, blk, 0, stream>>>(Wq, Wk, Wv, Wo, fc1_W, vqc_W, fc2_W, wreg,
                                       bq, bk, bv, bqkv, x, ln1_w, ln1_b, actb);
    // 1. fused QKV projection (direct, dbuf, 576 blocks) + qn/kn side outputs
    gemm_bf16<3, 64><<<dim3(18, 32, 1), blk, 0, stream>>>(actb, 768, Wqkvb, 768, bqkv,
                                                          Qb, 768, 0, Kfb, Vfb, 2304, 768, 0,
                                                          qnG, knG);
    // 2. MFMA attention, intra-block KV-split, LDS-staged K/V (R12 structure),
    //    fp32 norms from tables, XCD-affinity swizzled 768 blocks (3/CU)
    attn_mfma<<<768, blk, 0, stream>>>(Qb, Kfb, Vfb, pond, qnG, knG, actb);
    // 3. Wo split-K x4 (768 blocks = 3/CU)
    gemm_bf16<5, 64><<<dim3(6, 32, 4), blk, 0, stream>>>(actb, 768, Wob, 768, nullptr,
                                                         partb, 768, SP,
                                                         nullptr, nullptr, 768, 192, 0,
                                                         nullptr, nullptr);
    // 4. reduce + bo + residual(x) -> x2 fp32, fused ln2 -> actb
    reduce_wo_ln<<<2048, blk, 0, stream>>>(partb, bo, x, ln2_w, ln2_b, x2, actb);
    // 5. fc1 split-K x4, cols 0..767 only (768 blocks = 3/CU exact)
    gemm_bf16<5, 64><<<dim3(6, 32, 4), blk, 0, stream>>>(actb, 768, fc1b, 768, nullptr,
                                                         partb, 768, SP,
                                                         nullptr, nullptr, 768, 192, 0,
                                                         nullptr, nullptr);
    // 6. reduce + bias + cols 768..770 dots + expand -> Avqc [8192][768]
    reduce_fc1_expand<<<2048, blk, 0, stream>>>(partb, fc1_b, actb, fc1b + 768 * 768, Avqc);
    // 7. vqc (direct) + bias + gelu + transpose scatter (768 blocks = 3/CU)
    gemm_bf16<2, 64><<<dim3(6, 128, 1), blk, 0, stream>>>(Avqc, 768, vqcb, 768, vqc_b,
                                                          g, 3072, 0, nullptr, nullptr, 768, 768, 1,
                                                          nullptr, nullptr);
    // 8. fc2 split-K x4 (768 blocks = 3/CU)
    gemm_bf16<5, 64><<<dim3(6, 32, 4), blk, 0, stream>>>(g, 3072, fc2b, 3072, nullptr,
                                                         partb, 768, SP,
                                                         nullptr, nullptr, 768, 768, 0,
                                                         nullptr, nullptr);
    // 9. reduce + bias + residual(x2) -> out fp32
    reduce_fc2<<<1536, blk, 0, stream>>>(partb, fc2_b, x2, out);
}